// Round 1
// baseline (1464.554 us; speedup 1.0000x reference)
//
#include <hip/hip_runtime.h>

typedef unsigned short u16;
typedef __bf16 bf16x8 __attribute__((ext_vector_type(8)));
typedef float f32x4 __attribute__((ext_vector_type(4)));

#define NROWS 65536  // B*S = 512*128

__device__ __forceinline__ u16 f2bf(float f) {
  union { float f; unsigned u; } c; c.f = f;
  unsigned u = c.u;
  return (u16)((u + 0x7FFFu + ((u >> 16) & 1u)) >> 16);  // RNE
}

// A layout: [32 chunks][65536 rows][32] bf16  (row = b*128 + l, ci = cc*32 + c)
__global__ __launch_bounds__(256) void build_A(
    const float* __restrict__ W, const int* __restrict__ p1, const int* __restrict__ p2,
    const float* __restrict__ pe1, const float* __restrict__ pe2, u16* __restrict__ A) {
  int row = blockIdx.x;
  int t = threadIdx.x;  // handles ci = t*4 .. t*4+3
  float v[4];
  if (t < 225) {  // ci 0..899 from W, 900%16B-aligned float4
    const float4 f = *(const float4*)(W + (size_t)row * 900 + t * 4);
    v[0] = f.x; v[1] = f.y; v[2] = f.z; v[3] = f.w;
  } else if (t < 250) {  // ci 900..999 from pos embeddings
    int j0 = (t - 225) * 4;
    int i1 = p1[row], i2 = p2[row];
#pragma unroll
    for (int q = 0; q < 4; ++q) {
      int j = j0 + q;
      v[q] = (j < 50) ? pe1[i1 * 50 + j] : pe2[i2 * 50 + (j - 50)];
    }
  } else {  // ci 1000..1023 zero pad
    v[0] = v[1] = v[2] = v[3] = 0.f;
  }
  ushort4 o;
  o.x = f2bf(v[0]); o.y = f2bf(v[1]); o.z = f2bf(v[2]); o.w = f2bf(v[3]);
  int cc = t >> 3;
  int c4 = (t & 7) * 4;
  *(ushort4*)(A + ((size_t)cc * NROWS + row) * 32 + c4) = o;
}

// Wout layout: [15 gt][32 cc][256 co][32 ci] bf16; gt: 0-2=k3 taps, 3-7=k5, 8-14=k7
__global__ __launch_bounds__(256) void build_W(
    const float* __restrict__ w3, const float* __restrict__ w5, const float* __restrict__ w7,
    u16* __restrict__ Wout) {
  int co = blockIdx.x, gt = blockIdx.y, t = threadIdx.x;
  int g = gt < 3 ? 0 : (gt < 8 ? 1 : 2);
  int tap = gt - (g == 0 ? 0 : (g == 1 ? 3 : 8));
  int k = (g == 0 ? 3 : (g == 1 ? 5 : 7));
  const float* src = (g == 0 ? w3 : (g == 1 ? w5 : w7));
  ushort4 o;
#pragma unroll
  for (int q = 0; q < 4; ++q) {
    int ci = t * 4 + q;
    float f = (ci < 1000) ? src[((size_t)co * 1000 + ci) * k + tap] : 0.f;
    ((u16*)&o)[q] = f2bf(f);
  }
  int cc = t >> 3;
  int c4 = (t & 7) * 4;
  *(ushort4*)(Wout + (((size_t)gt * 32 + cc) * 256 + co) * 32 + c4) = o;
}

// One WG: batch b, channel tile of 128, all 128 output positions.
// M=128 (l), N=128 (co), K-dim = 1024 ci x K taps. Waves 2x2, each 64x64.
template <int K>
__global__ __launch_bounds__(256) void conv_gemm(
    const u16* __restrict__ A, const u16* __restrict__ Wg,
    const float* __restrict__ bias, const int* __restrict__ e1p, const int* __restrict__ e2p,
    float* __restrict__ pooled, int g) {
  constexpr int P = K / 2;
  constexpr int R = 128 + 2 * P;        // staged rows incl. halo; r <-> l = r - P
  constexpr int TB = (K < 4) ? K : 4;   // taps per stage phase
  __shared__ __align__(16) u16 Alds[R][40];          // 80B rows: even bank spread
  __shared__ __align__(16) u16 Blds[TB][128][40];
  __shared__ float pool[3][128];

  const int tid = threadIdx.x;
  const int b = blockIdx.y;
  const int co_base = blockIdx.x * 128;
  const int lane = tid & 63;
  const int w = tid >> 6;
  const int wm = w >> 1, wn = w & 1;
  const int l15 = lane & 15;
  const int kg8 = (lane >> 4) * 8;
  const int mbase = wm * 64 + l15;
  const int nbase = wn * 64 + l15;

  f32x4 acc[4][4];
  const f32x4 vzero = {0.f, 0.f, 0.f, 0.f};
#pragma unroll
  for (int i = 0; i < 4; ++i)
#pragma unroll
    for (int j = 0; j < 4; ++j) acc[i][j] = vzero;

  for (int cc = 0; cc < 32; ++cc) {
    // stage A tile (with zero halo)
    for (int u = tid; u < R * 4; u += 256) {
      int r = u >> 2, part = u & 3;
      int l = r - P;
      uint4 val = make_uint4(0u, 0u, 0u, 0u);
      if (l >= 0 && l < 128)
        val = *(const uint4*)(A + ((size_t)cc * NROWS + b * 128 + l) * 32 + part * 8);
      *(uint4*)(&Alds[r][part * 8]) = val;
    }
    // stage B taps [0, TB)
    for (int u = tid; u < TB * 512; u += 256) {
      int tr = u >> 9, co = (u >> 2) & 127, part = u & 3;
      uint4 val = *(const uint4*)(Wg + (((size_t)tr * 32 + cc) * 256 + co_base + co) * 32 + part * 8);
      *(uint4*)(&Blds[tr][co][part * 8]) = val;
    }
    __syncthreads();
#pragma unroll
    for (int tr = 0; tr < TB; ++tr) {
      bf16x8 af[4], bfr[4];
#pragma unroll
      for (int mf = 0; mf < 4; ++mf)
        af[mf] = *(const bf16x8*)(&Alds[mbase + mf * 16 + tr][kg8]);
#pragma unroll
      for (int nf = 0; nf < 4; ++nf)
        bfr[nf] = *(const bf16x8*)(&Blds[tr][nbase + nf * 16][kg8]);
#pragma unroll
      for (int mf = 0; mf < 4; ++mf)
#pragma unroll
        for (int nf = 0; nf < 4; ++nf)
          acc[mf][nf] = __builtin_amdgcn_mfma_f32_16x16x32_bf16(af[mf], bfr[nf], acc[mf][nf], 0, 0, 0);
    }
    __syncthreads();
    if constexpr (K > 4) {
      // stage + compute taps [4, K)
      for (int u = tid; u < (K - 4) * 512; u += 256) {
        int tr = u >> 9, co = (u >> 2) & 127, part = u & 3;
        uint4 val = *(const uint4*)(Wg + ((((size_t)(4 + tr)) * 32 + cc) * 256 + co_base + co) * 32 + part * 8);
        *(uint4*)(&Blds[tr][co][part * 8]) = val;
      }
      __syncthreads();
#pragma unroll
      for (int tr = 0; tr < K - 4; ++tr) {
        bf16x8 af[4], bfr[4];
#pragma unroll
        for (int mf = 0; mf < 4; ++mf)
          af[mf] = *(const bf16x8*)(&Alds[mbase + mf * 16 + 4 + tr][kg8]);
#pragma unroll
        for (int nf = 0; nf < 4; ++nf)
          bfr[nf] = *(const bf16x8*)(&Blds[tr][nbase + nf * 16][kg8]);
#pragma unroll
        for (int mf = 0; mf < 4; ++mf)
#pragma unroll
          for (int nf = 0; nf < 4; ++nf)
            acc[mf][nf] = __builtin_amdgcn_mfma_f32_16x16x32_bf16(af[mf], bfr[nf], acc[mf][nf], 0, 0, 0);
      }
      __syncthreads();
    }
  }

  // epilogue: tanh + bias, piecewise segment pooling
  for (int u = tid; u < 384; u += 256) ((float*)pool)[u] = 0.f;
  __syncthreads();
  int a1 = e1p[b], a2 = e2p[b];
  int d1 = a1 < a2 ? a1 : a2;
  int d2 = a1 < a2 ? a2 : a1;
  float bs[4];
#pragma unroll
  for (int nf = 0; nf < 4; ++nf) bs[nf] = bias[co_base + nbase + nf * 16];
#pragma unroll
  for (int mf = 0; mf < 4; ++mf) {
#pragma unroll
    for (int nf = 0; nf < 4; ++nf) {
#pragma unroll
      for (int r4 = 0; r4 < 4; ++r4) {
        int l = wm * 64 + mf * 16 + (lane >> 4) * 4 + r4;  // C/D: col=lane&15, row=(lane>>4)*4+reg
        if (l < 127) {  // position S-1 belongs to no segment
          float v = tanhf(acc[mf][nf][r4] + bs[nf]);
          int seg = l < d1 ? 0 : (l < d2 ? 1 : 2);
          atomicAdd(&pool[seg][nbase + nf * 16], v);
        }
      }
    }
  }
  __syncthreads();
  float cnt0 = (float)d1, cnt1 = (float)(d2 - d1), cnt2 = (float)(127 - d2);
  for (int u = tid; u < 384; u += 256) {
    int seg = u >> 7, col = u & 127;
    float c = seg == 0 ? cnt0 : (seg == 1 ? cnt1 : cnt2);
    c = fmaxf(c, 1.f);
    pooled[((size_t)b * 768 + g * 256 + co_base + col) * 3 + seg] = pool[seg][col] / c;
  }
}

// logits = [e1|e2|pooled_flat] @ fc_w^T + fc_b ; softmax over 19
__global__ __launch_bounds__(256) void fc_softmax(
    const float* __restrict__ e1, const float* __restrict__ e2,
    const float* __restrict__ pooled, const float* __restrict__ fcw,
    const float* __restrict__ fcb, float* __restrict__ out) {
  int b = blockIdx.x, tid = threadIdx.x;
  float acc[19];
#pragma unroll
  for (int r = 0; r < 19; ++r) acc[r] = 0.f;
  for (int j = tid; j < 2904; j += 256) {
    float v;
    if (j < 300) v = e1[b * 300 + j];
    else if (j < 600) v = e2[b * 300 + (j - 300)];
    else v = pooled[(size_t)b * 2304 + (j - 600)];
#pragma unroll
    for (int r = 0; r < 19; ++r) acc[r] = fmaf(v, fcw[r * 2904 + j], acc[r]);
  }
#pragma unroll
  for (int r = 0; r < 19; ++r) {
#pragma unroll
    for (int off = 32; off > 0; off >>= 1) acc[r] += __shfl_down(acc[r], off);
  }
  __shared__ float red[4][19];
  if ((tid & 63) == 0) {
#pragma unroll
    for (int r = 0; r < 19; ++r) red[tid >> 6][r] = acc[r];
  }
  __syncthreads();
  if (tid == 0) {
    float lg[19], mx = -1e30f;
#pragma unroll
    for (int r = 0; r < 19; ++r) {
      lg[r] = red[0][r] + red[1][r] + red[2][r] + red[3][r] + fcb[r];
      mx = fmaxf(mx, lg[r]);
    }
    float s = 0.f;
#pragma unroll
    for (int r = 0; r < 19; ++r) { lg[r] = expf(lg[r] - mx); s += lg[r]; }
    float inv = 1.f / s;
#pragma unroll
    for (int r = 0; r < 19; ++r) out[b * 19 + r] = lg[r] * inv;
  }
}

extern "C" void kernel_launch(void* const* d_in, const int* in_sizes, int n_in,
                              void* d_out, int out_size, void* d_ws, size_t ws_size,
                              hipStream_t stream) {
  const float* W   = (const float*)d_in[0];
  const int* Wp1   = (const int*)d_in[1];
  const int* Wp2   = (const int*)d_in[2];
  const float* e1  = (const float*)d_in[3];
  const float* e2  = (const float*)d_in[4];
  const int* e1p   = (const int*)d_in[5];
  const int* e2p   = (const int*)d_in[6];
  const float* pe1 = (const float*)d_in[7];
  const float* pe2 = (const float*)d_in[8];
  const float* fcw = (const float*)d_in[9];
  const float* fcb = (const float*)d_in[10];
  const float* w3  = (const float*)d_in[11];
  const float* b3  = (const float*)d_in[12];
  const float* w5  = (const float*)d_in[13];
  const float* b5  = (const float*)d_in[14];
  const float* w7  = (const float*)d_in[15];
  const float* b7  = (const float*)d_in[16];
  float* out = (float*)d_out;

  // workspace layout
  const size_t A_BYTES = (size_t)32 * NROWS * 32 * 2;          // 134,217,728
  const size_t W_BYTES = (size_t)15 * 32 * 256 * 32 * 2;       //   7,864,320
  const size_t P_BYTES = (size_t)512 * 768 * 3 * 4;            //   4,718,592
  if (ws_size < A_BYTES + W_BYTES + P_BYTES) return;           // need ~140 MiB scratch
  char* ws = (char*)d_ws;
  u16* Abf = (u16*)ws;
  u16* Wbf = (u16*)(ws + A_BYTES);
  float* pooled = (float*)(ws + A_BYTES + W_BYTES);

  build_A<<<dim3(NROWS), 256, 0, stream>>>(W, Wp1, Wp2, pe1, pe2, Abf);
  build_W<<<dim3(256, 15), 256, 0, stream>>>(w3, w5, w7, Wbf);
  conv_gemm<3><<<dim3(2, 512), 256, 0, stream>>>(Abf, Wbf + (size_t)0 * 32 * 256 * 32, b3, e1p, e2p, pooled, 0);
  conv_gemm<5><<<dim3(2, 512), 256, 0, stream>>>(Abf, Wbf + (size_t)3 * 32 * 256 * 32, b5, e1p, e2p, pooled, 1);
  conv_gemm<7><<<dim3(2, 512), 256, 0, stream>>>(Abf, Wbf + (size_t)8 * 32 * 256 * 32, b7, e1p, e2p, pooled, 2);
  fc_softmax<<<dim3(512), 256, 0, stream>>>(e1, e2, pooled, fcw, fcb, out);
}

// Round 2
// 1105.849 us; speedup vs baseline: 1.3244x; 1.3244x over previous
//
#include <hip/hip_runtime.h>

typedef unsigned short u16;
typedef __bf16 bf16x8 __attribute__((ext_vector_type(8)));
typedef float f32x4 __attribute__((ext_vector_type(4)));

#define NROWS 65536  // B*S = 512*128

__device__ __forceinline__ u16 f2bf(float f) {
  union { float f; unsigned u; } c; c.f = f;
  unsigned u = c.u;
  return (u16)((u + 0x7FFFu + ((u >> 16) & 1u)) >> 16);  // RNE
}

// A layout: [32 chunks][65536 rows][32] bf16  (row = b*128 + l, ci = cc*32 + c)
// block: 4 consecutive rows; thread t: row +(t>>6), ci base (t&63)*16 -> 32B store
__global__ __launch_bounds__(256) void build_A(
    const float* __restrict__ W, const int* __restrict__ p1, const int* __restrict__ p2,
    const float* __restrict__ pe1, const float* __restrict__ pe2, u16* __restrict__ A) {
  const int r = blockIdx.x * 4 + (threadIdx.x >> 6);
  const int cb = (threadIdx.x & 63) * 16;
  float v[16];
  if (cb + 15 < 900) {
#pragma unroll
    for (int q = 0; q < 4; ++q) {
      const float4 f = *(const float4*)(W + (size_t)r * 900 + cb + q * 4);
      v[q * 4 + 0] = f.x; v[q * 4 + 1] = f.y; v[q * 4 + 2] = f.z; v[q * 4 + 3] = f.w;
    }
  } else {
    const int i1 = p1[r], i2 = p2[r];
#pragma unroll
    for (int q = 0; q < 16; ++q) {
      const int ci = cb + q;
      float f;
      if (ci < 900) f = W[(size_t)r * 900 + ci];
      else if (ci < 950) f = pe1[i1 * 50 + (ci - 900)];
      else if (ci < 1000) f = pe2[i2 * 50 + (ci - 950)];
      else f = 0.f;
      v[q] = f;
    }
  }
  u16 o[16];
#pragma unroll
  for (int q = 0; q < 16; ++q) o[q] = f2bf(v[q]);
  u16* dst = A + ((size_t)(cb >> 5) * NROWS + r) * 32 + (cb & 31);
  *(uint4*)(dst) = *(const uint4*)(&o[0]);
  *(uint4*)(dst + 8) = *(const uint4*)(&o[8]);
}

// Wout layout: [15 gt][32 cc][256 co][32 ci] bf16; gt: 0-2=k3 taps, 3-7=k5, 8-14=k7
__global__ __launch_bounds__(256) void build_W(
    const float* __restrict__ w3, const float* __restrict__ w5, const float* __restrict__ w7,
    u16* __restrict__ Wout) {
  int co = blockIdx.x, gt = blockIdx.y, t = threadIdx.x;
  int g = gt < 3 ? 0 : (gt < 8 ? 1 : 2);
  int tap = gt - (g == 0 ? 0 : (g == 1 ? 3 : 8));
  int k = (g == 0 ? 3 : (g == 1 ? 5 : 7));
  const float* src = (g == 0 ? w3 : (g == 1 ? w5 : w7));
  ushort4 o;
#pragma unroll
  for (int q = 0; q < 4; ++q) {
    int ci = t * 4 + q;
    float f = (ci < 1000) ? src[((size_t)co * 1000 + ci) * k + tap] : 0.f;
    ((u16*)&o)[q] = f2bf(f);
  }
  int cc = t >> 3;
  int c4 = (t & 7) * 4;
  *(ushort4*)(Wout + (((size_t)gt * 32 + cc) * 256 + co) * 32 + c4) = o;
}

// One WG: batch b, co tile 128, M=128 positions. Waves 2x2, each 64x64.
// Staging via global_load_lds(16B): LDS linear, halo rows zeroed once.
template <int K>
__global__ __launch_bounds__(256) void conv_gemm(
    const u16* __restrict__ A, const u16* __restrict__ Wg,
    const float* __restrict__ bias, const int* __restrict__ e1p, const int* __restrict__ e2p,
    float* __restrict__ pooled, int g) {
  constexpr int P = K / 2;
  constexpr int R = 128 + 2 * P;  // LDS row = l + P
  __shared__ __align__(16) u16 Alds[R][32];
  __shared__ __align__(16) u16 Blds[K][128][32];
  __shared__ float pool[3][128];

  const int tid = threadIdx.x;
  const int b = blockIdx.y;
  const int co_base = blockIdx.x * 128;
  const int lane = tid & 63;
  const int w = tid >> 6;
  const int wm = w >> 1, wn = w & 1;
  const int l15 = lane & 15;
  const int kg8 = (lane >> 4) * 8;
  const int mbase = wm * 64 + l15;
  const int nbase = wn * 64 + l15;

  // zero the halo rows once (stay zero: staging only writes middle 128 rows)
  if (tid < 2 * P * 32) {
    int hr = tid >> 5, c = tid & 31;
    int row = (hr < P) ? hr : (128 + hr);
    Alds[row][c] = 0;
  }

  f32x4 acc[4][4];
  const f32x4 vzero = {0.f, 0.f, 0.f, 0.f};
#pragma unroll
  for (int i = 0; i < 4; ++i)
#pragma unroll
    for (int j = 0; j < 4; ++j) acc[i][j] = vzero;

  const int woff = w * 2048;  // per-wave staging byte range within an 8KB tile

  for (int cc = 0; cc < 32; ++cc) {
    // stage A middle 128 rows (8KB) direct to LDS
    {
      const char* gp = (const char*)(A + ((size_t)cc * NROWS + b * 128) * 32);
      char* lp = (char*)(&Alds[P][0]);
#pragma unroll
      for (int j = 0; j < 2; ++j) {
        int off = woff + j * 1024;
        __builtin_amdgcn_global_load_lds(
            (const __attribute__((address_space(1))) unsigned int*)(gp + off + lane * 16),
            (__attribute__((address_space(3))) unsigned int*)(lp + off), 16, 0, 0);
      }
    }
    // stage B: K taps x 8KB each
#pragma unroll
    for (int t = 0; t < K; ++t) {
      const char* gp = (const char*)(Wg + (((size_t)t * 32 + cc) * 256 + co_base) * 32);
      char* lp = (char*)(&Blds[t][0][0]);
#pragma unroll
      for (int j = 0; j < 2; ++j) {
        int off = woff + j * 1024;
        __builtin_amdgcn_global_load_lds(
            (const __attribute__((address_space(1))) unsigned int*)(gp + off + lane * 16),
            (__attribute__((address_space(3))) unsigned int*)(lp + off), 16, 0, 0);
      }
    }
    __syncthreads();  // vmcnt(0)+lgkmcnt drain at barrier
#pragma unroll
    for (int tr = 0; tr < K; ++tr) {
      bf16x8 af[4], bfr[4];
#pragma unroll
      for (int mf = 0; mf < 4; ++mf)
        af[mf] = *(const bf16x8*)(&Alds[mbase + mf * 16 + tr][kg8]);
#pragma unroll
      for (int nf = 0; nf < 4; ++nf)
        bfr[nf] = *(const bf16x8*)(&Blds[tr][nbase + nf * 16][kg8]);
#pragma unroll
      for (int mf = 0; mf < 4; ++mf)
#pragma unroll
        for (int nf = 0; nf < 4; ++nf)
          acc[mf][nf] = __builtin_amdgcn_mfma_f32_16x16x32_bf16(af[mf], bfr[nf], acc[mf][nf], 0, 0, 0);
    }
    __syncthreads();
  }

  // epilogue: tanh + bias, piecewise segment pooling
  for (int u = tid; u < 384; u += 256) ((float*)pool)[u] = 0.f;
  __syncthreads();
  int a1 = e1p[b], a2 = e2p[b];
  int d1 = a1 < a2 ? a1 : a2;
  int d2 = a1 < a2 ? a2 : a1;
  float bs[4];
#pragma unroll
  for (int nf = 0; nf < 4; ++nf) bs[nf] = bias[co_base + nbase + nf * 16];
#pragma unroll
  for (int mf = 0; mf < 4; ++mf) {
#pragma unroll
    for (int nf = 0; nf < 4; ++nf) {
#pragma unroll
      for (int r4 = 0; r4 < 4; ++r4) {
        int l = wm * 64 + mf * 16 + (lane >> 4) * 4 + r4;  // C/D: col=lane&15, row=(lane>>4)*4+reg
        if (l < 127) {  // position S-1 belongs to no segment
          float v = tanhf(acc[mf][nf][r4] + bs[nf]);
          int seg = l < d1 ? 0 : (l < d2 ? 1 : 2);
          atomicAdd(&pool[seg][nbase + nf * 16], v);
        }
      }
    }
  }
  __syncthreads();
  float cnt0 = (float)d1, cnt1 = (float)(d2 - d1), cnt2 = (float)(127 - d2);
  for (int u = tid; u < 384; u += 256) {
    int seg = u >> 7, col = u & 127;
    float c = seg == 0 ? cnt0 : (seg == 1 ? cnt1 : cnt2);
    c = fmaxf(c, 1.f);
    pooled[((size_t)b * 768 + g * 256 + co_base + col) * 3 + seg] = pool[seg][col] / c;
  }
}

// logits = [e1|e2|pooled_flat] @ fc_w^T + fc_b ; softmax over 19
__global__ __launch_bounds__(256) void fc_softmax(
    const float* __restrict__ e1, const float* __restrict__ e2,
    const float* __restrict__ pooled, const float* __restrict__ fcw,
    const float* __restrict__ fcb, float* __restrict__ out) {
  int b = blockIdx.x, tid = threadIdx.x;
  float acc[19];
#pragma unroll
  for (int r = 0; r < 19; ++r) acc[r] = 0.f;
  for (int j = tid; j < 2904; j += 256) {
    float v;
    if (j < 300) v = e1[b * 300 + j];
    else if (j < 600) v = e2[b * 300 + (j - 300)];
    else v = pooled[(size_t)b * 2304 + (j - 600)];
#pragma unroll
    for (int r = 0; r < 19; ++r) acc[r] = fmaf(v, fcw[r * 2904 + j], acc[r]);
  }
#pragma unroll
  for (int r = 0; r < 19; ++r) {
#pragma unroll
    for (int off = 32; off > 0; off >>= 1) acc[r] += __shfl_down(acc[r], off);
  }
  __shared__ float red[4][19];
  if ((tid & 63) == 0) {
#pragma unroll
    for (int r = 0; r < 19; ++r) red[tid >> 6][r] = acc[r];
  }
  __syncthreads();
  if (tid == 0) {
    float lg[19], mx = -1e30f;
#pragma unroll
    for (int r = 0; r < 19; ++r) {
      lg[r] = red[0][r] + red[1][r] + red[2][r] + red[3][r] + fcb[r];
      mx = fmaxf(mx, lg[r]);
    }
    float s = 0.f;
#pragma unroll
    for (int r = 0; r < 19; ++r) { lg[r] = expf(lg[r] - mx); s += lg[r]; }
    float inv = 1.f / s;
#pragma unroll
    for (int r = 0; r < 19; ++r) out[b * 19 + r] = lg[r] * inv;
  }
}

extern "C" void kernel_launch(void* const* d_in, const int* in_sizes, int n_in,
                              void* d_out, int out_size, void* d_ws, size_t ws_size,
                              hipStream_t stream) {
  const float* W   = (const float*)d_in[0];
  const int* Wp1   = (const int*)d_in[1];
  const int* Wp2   = (const int*)d_in[2];
  const float* e1  = (const float*)d_in[3];
  const float* e2  = (const float*)d_in[4];
  const int* e1p   = (const int*)d_in[5];
  const int* e2p   = (const int*)d_in[6];
  const float* pe1 = (const float*)d_in[7];
  const float* pe2 = (const float*)d_in[8];
  const float* fcw = (const float*)d_in[9];
  const float* fcb = (const float*)d_in[10];
  const float* w3  = (const float*)d_in[11];
  const float* b3  = (const float*)d_in[12];
  const float* w5  = (const float*)d_in[13];
  const float* b5  = (const float*)d_in[14];
  const float* w7  = (const float*)d_in[15];
  const float* b7  = (const float*)d_in[16];
  float* out = (float*)d_out;

  const size_t A_BYTES = (size_t)32 * NROWS * 32 * 2;          // 134,217,728
  const size_t W_BYTES = (size_t)15 * 32 * 256 * 32 * 2;       //   7,864,320
  const size_t P_BYTES = (size_t)512 * 768 * 3 * 4;            //   4,718,592
  if (ws_size < A_BYTES + W_BYTES + P_BYTES) return;           // need ~140 MiB scratch
  char* ws = (char*)d_ws;
  u16* Abf = (u16*)ws;
  u16* Wbf = (u16*)(ws + A_BYTES);
  float* pooled = (float*)(ws + A_BYTES + W_BYTES);

  build_A<<<dim3(NROWS / 4), 256, 0, stream>>>(W, Wp1, Wp2, pe1, pe2, Abf);
  build_W<<<dim3(256, 15), 256, 0, stream>>>(w3, w5, w7, Wbf);
  conv_gemm<3><<<dim3(2, 512), 256, 0, stream>>>(Abf, Wbf + (size_t)0 * 32 * 256 * 32, b3, e1p, e2p, pooled, 0);
  conv_gemm<5><<<dim3(2, 512), 256, 0, stream>>>(Abf, Wbf + (size_t)3 * 32 * 256 * 32, b5, e1p, e2p, pooled, 1);
  conv_gemm<7><<<dim3(2, 512), 256, 0, stream>>>(Abf, Wbf + (size_t)8 * 32 * 256 * 32, b7, e1p, e2p, pooled, 2);
  fc_softmax<<<dim3(512), 256, 0, stream>>>(e1, e2, pooled, fcw, fcb, out);
}

// Round 3
// 862.055 us; speedup vs baseline: 1.6989x; 1.2828x over previous
//
#include <hip/hip_runtime.h>

typedef unsigned short u16;
typedef __bf16 bf16x8 __attribute__((ext_vector_type(8)));
typedef float f32x4 __attribute__((ext_vector_type(4)));

#define NROWS 65536  // B*S = 512*128

__device__ __forceinline__ u16 f2bf(float f) {
  union { float f; unsigned u; } c; c.f = f;
  unsigned u = c.u;
  return (u16)((u + 0x7FFFu + ((u >> 16) & 1u)) >> 16);  // RNE
}

template <int N> __device__ __forceinline__ void vmcnt_wait() {
  if constexpr (N == 0) asm volatile("s_waitcnt vmcnt(0)" ::: "memory");
  else if constexpr (N == 2) asm volatile("s_waitcnt vmcnt(2)" ::: "memory");
  else if constexpr (N == 4) asm volatile("s_waitcnt vmcnt(4)" ::: "memory");
  else if constexpr (N == 6) asm volatile("s_waitcnt vmcnt(6)" ::: "memory");
  else if constexpr (N == 8) asm volatile("s_waitcnt vmcnt(8)" ::: "memory");
  else if constexpr (N == 10) asm volatile("s_waitcnt vmcnt(10)" ::: "memory");
}

__device__ __forceinline__ void gll16(const void* g, void* l) {
  __builtin_amdgcn_global_load_lds(
      (const __attribute__((address_space(1))) unsigned int*)g,
      (__attribute__((address_space(3))) unsigned int*)l, 16, 0, 0);
}

// A layout: [32 chunks][65536 rows][32] bf16  (row = b*128 + l, ci = cc*32 + c)
__global__ __launch_bounds__(256) void build_A(
    const float* __restrict__ W, const int* __restrict__ p1, const int* __restrict__ p2,
    const float* __restrict__ pe1, const float* __restrict__ pe2, u16* __restrict__ A) {
  const int r = blockIdx.x * 4 + (threadIdx.x >> 6);
  const int cb = (threadIdx.x & 63) * 16;
  float v[16];
  if (cb + 15 < 900) {
#pragma unroll
    for (int q = 0; q < 4; ++q) {
      const float4 f = *(const float4*)(W + (size_t)r * 900 + cb + q * 4);
      v[q * 4 + 0] = f.x; v[q * 4 + 1] = f.y; v[q * 4 + 2] = f.z; v[q * 4 + 3] = f.w;
    }
  } else {
    const int i1 = p1[r], i2 = p2[r];
#pragma unroll
    for (int q = 0; q < 16; ++q) {
      const int ci = cb + q;
      float f;
      if (ci < 900) f = W[(size_t)r * 900 + ci];
      else if (ci < 950) f = pe1[i1 * 50 + (ci - 900)];
      else if (ci < 1000) f = pe2[i2 * 50 + (ci - 950)];
      else f = 0.f;
      v[q] = f;
    }
  }
  u16 o[16];
#pragma unroll
  for (int q = 0; q < 16; ++q) o[q] = f2bf(v[q]);
  u16* dst = A + ((size_t)(cb >> 5) * NROWS + r) * 32 + (cb & 31);
  *(uint4*)(dst) = *(const uint4*)(&o[0]);
  *(uint4*)(dst + 8) = *(const uint4*)(&o[8]);
}

// Wout: [15 gt][32 cc][256 co][32 ci] bf16, ci-chunks XOR-swizzled by (co>>1)&3.
__global__ __launch_bounds__(256) void build_W(
    const float* __restrict__ w3, const float* __restrict__ w5, const float* __restrict__ w7,
    u16* __restrict__ Wout) {
  int co = blockIdx.x, gt = blockIdx.y, t = threadIdx.x;
  int g = gt < 3 ? 0 : (gt < 8 ? 1 : 2);
  int tap = gt - (g == 0 ? 0 : (g == 1 ? 3 : 8));
  int k = (g == 0 ? 3 : (g == 1 ? 5 : 7));
  const float* src = (g == 0 ? w3 : (g == 1 ? w5 : w7));
  ushort4 o;
#pragma unroll
  for (int q = 0; q < 4; ++q) {
    int ci = t * 4 + q;
    float f = (ci < 1000) ? src[((size_t)co * 1000 + ci) * k + tap] : 0.f;
    ((u16*)&o)[q] = f2bf(f);
  }
  int cc = t >> 3;
  int s = (t & 7) >> 1;                  // 16B chunk 0..3
  int swz = ((co >> 1) & 3);
  int c4 = ((s ^ swz) * 8) + (t & 1) * 4;
  *(ushort4*)(Wout + (((size_t)gt * 32 + cc) * 256 + co) * 32 + c4) = o;
}

// One WG: 2 batch rows (b-pair), all 256 co, 128 positions each. 8 waves: wm(b)x wn(4).
// A: 80B-padded LDS rows (bank-walk, conflict-free), double-buffered.
// B: XOR-swizzled 64B rows, split into tap-halves H0/H1, counted-vmcnt pipeline.
template <int K, int G>
__global__ __launch_bounds__(512, 2) void conv_gemm(
    const u16* __restrict__ A, const u16* __restrict__ Wg,
    const float* __restrict__ bias, const int* __restrict__ e1p, const int* __restrict__ e2p,
    float* __restrict__ pooled) {
  constexpr int P = K / 2;
  constexpr int T0 = (K + 1) / 2;      // taps in half 0 (4/3/2)
  constexpr int T1 = K - T0;           // taps in half 1 (3/2/1)
  constexpr int ABUFB = 10752;         // per-b region: 134 rows x 80B, padded to x128
  constexpr int AREG = 2 * ABUFB;      // per abuf (both b's) = 21504
  constexpr int BOFF = 2 * AREG;       // = 43008, B region start
  __shared__ __align__(128) char smem[BOFF + K * 16384];

  const int tid = threadIdx.x;
  const int lane = tid & 63;
  const int w = tid >> 6;
  const int wm = w >> 2;               // which b of the pair
  const int wn = w & 3;                // co quarter
  const int l15 = lane & 15;
  const int kg = lane >> 4;
  const int bg0 = blockIdx.x * 2;

  // per-thread LDS read bases
  const int a_thr = wm * ABUFB + l15 * 80 + kg * 16;                      // + ab*AREG + (mf*16+t+3-P)*80
  const int b_thr = BOFF + (wn * 64 + l15) * 64 + ((kg ^ ((l15 >> 1) & 3)) << 4);  // + t*16384 + nf*1024

  // zero halo rows (rows 0..2 and 131..133 of each b region, both abufs), once
  for (int u = tid; u < 480; u += 512) {
    int reg = u / 120, q = u - reg * 120;
    int base = reg * ABUFB;  // reg 0..3 = ab0b0, ab0b1, ab1b0, ab1b1
    int byte = base + (q < 60 ? q * 4 : 10480 + (q - 60) * 4);
    *(unsigned*)(smem + byte) = 0u;
  }
  __syncthreads();

  // ---- staging helpers ----
  auto stage_A = [&](int cc, int ab) {
    for (int u = w; u < 20; u += 8) {
      int bb = u < 10 ? 0 : 1;
      int j = u - bb * 10;
      char* lp = smem + ab * AREG + bb * ABUFB + 240 + j * 1024;
      int n = 15 + (j << 6) + lane;          // 16B-chunk index from region start
      int row = (n * 13108) >> 16;           // n/5 (80B rows = 5 chunks)
      int c = n - row * 5; c = c > 3 ? 3 : c;
      const u16* gp = A + ((size_t)cc * NROWS + (size_t)(bg0 + bb) * 128 + (row - 3)) * 32 + c * 8;
      gll16(gp, lp);
    }
  };
  auto stage_B = [&](int cc, int t0, int tcnt) {
    for (int u = w; u < tcnt * 16; u += 8) {
      int t = t0 + (u >> 4), j = u & 15;
      char* lp = smem + BOFF + t * 16384 + j * 1024;
      const u16* gp = Wg + ((size_t)(t * 32 + cc)) * 8192 + j * 512 + lane * 8;
      gll16(gp, lp);
    }
  };

  f32x4 acc[8][4];
  const f32x4 vz = {0.f, 0.f, 0.f, 0.f};
#pragma unroll
  for (int i = 0; i < 8; ++i)
#pragma unroll
    for (int j = 0; j < 4; ++j) acc[i][j] = vz;

  // prologue: A(0) + H0(0)
  stage_A(0, 0);
  stage_B(0, 0, T0);

  for (int cc = 0; cc < 32; ++cc) {
    const int ab = cc & 1;
    const char* ap = smem + ab * AREG + a_thr;
    const char* bp = smem + b_thr;
    // ---- even half: compute taps [0,T0) ----
    stage_B(cc, T0, T1);
    vmcnt_wait<T1 * 2>();
    __builtin_amdgcn_s_barrier();
#pragma unroll
    for (int t = 0; t < T0; ++t) {
      bf16x8 af[8], bf[4];
#pragma unroll
      for (int mf = 0; mf < 8; ++mf)
        af[mf] = *(const bf16x8*)(ap + (mf * 16 + t + 3 - P) * 80);
#pragma unroll
      for (int nf = 0; nf < 4; ++nf)
        bf[nf] = *(const bf16x8*)(bp + t * 16384 + nf * 1024);
      __builtin_amdgcn_s_setprio(1);
#pragma unroll
      for (int mf = 0; mf < 8; ++mf)
#pragma unroll
        for (int nf = 0; nf < 4; ++nf)
          acc[mf][nf] = __builtin_amdgcn_mfma_f32_16x16x32_bf16(af[mf], bf[nf], acc[mf][nf], 0, 0, 0);
      __builtin_amdgcn_s_setprio(0);
    }
    __builtin_amdgcn_s_barrier();
    // ---- odd half: compute taps [T0,K) ----
    if (cc != 31) {
      stage_A(cc + 1, ab ^ 1);
      stage_B(cc + 1, 0, T0);
      vmcnt_wait<T0 * 2 + 2>();
    } else {
      vmcnt_wait<0>();
    }
    __builtin_amdgcn_s_barrier();
#pragma unroll
    for (int t = T0; t < K; ++t) {
      bf16x8 af[8], bf[4];
#pragma unroll
      for (int mf = 0; mf < 8; ++mf)
        af[mf] = *(const bf16x8*)(ap + (mf * 16 + t + 3 - P) * 80);
#pragma unroll
      for (int nf = 0; nf < 4; ++nf)
        bf[nf] = *(const bf16x8*)(bp + t * 16384 + nf * 1024);
      __builtin_amdgcn_s_setprio(1);
#pragma unroll
      for (int mf = 0; mf < 8; ++mf)
#pragma unroll
        for (int nf = 0; nf < 4; ++nf)
          acc[mf][nf] = __builtin_amdgcn_mfma_f32_16x16x32_bf16(af[mf], bf[nf], acc[mf][nf], 0, 0, 0);
      __builtin_amdgcn_s_setprio(0);
    }
    __builtin_amdgcn_s_barrier();
  }

  // ---- epilogue: tanh + piecewise segment pooling (pool overlays A region) ----
  __syncthreads();
  float* pool = (float*)smem;  // [2][3][256]
  for (int u = tid; u < 1536; u += 512) pool[u] = 0.f;
  __syncthreads();
  int a1 = e1p[bg0 + wm], a2 = e2p[bg0 + wm];
  int d1 = a1 < a2 ? a1 : a2;
  int d2 = a1 < a2 ? a2 : a1;
  float bs[4];
#pragma unroll
  for (int nf = 0; nf < 4; ++nf) bs[nf] = bias[wn * 64 + nf * 16 + l15];
#pragma unroll
  for (int nf = 0; nf < 4; ++nf) {
    float s0 = 0.f, s1 = 0.f, s2 = 0.f;
#pragma unroll
    for (int mf = 0; mf < 8; ++mf) {
#pragma unroll
      for (int r4 = 0; r4 < 4; ++r4) {
        int l = mf * 16 + kg * 4 + r4;  // C/D: col=lane&15, row=(lane>>4)*4+reg
        if (l < 127) {
          float x = acc[mf][nf][r4] + bs[nf];
          x = fminf(fmaxf(x, -8.f), 8.f);
          float e = __expf(2.f * x);
          float v = (e - 1.f) * __builtin_amdgcn_rcpf(e + 1.f);
          if (l < d1) s0 += v;
          else if (l < d2) s1 += v;
          else s2 += v;
        }
      }
    }
    int co = wn * 64 + nf * 16 + l15;
    atomicAdd(&pool[wm * 768 + 0 * 256 + co], s0);
    atomicAdd(&pool[wm * 768 + 1 * 256 + co], s1);
    atomicAdd(&pool[wm * 768 + 2 * 256 + co], s2);
  }
  __syncthreads();
  for (int u = tid; u < 1536; u += 512) {
    int bb = u >= 768 ? 1 : 0;
    int rem = u - bb * 768;
    int seg = rem >> 8, co = rem & 255;
    int a1b = e1p[bg0 + bb], a2b = e2p[bg0 + bb];
    int dd1 = a1b < a2b ? a1b : a2b;
    int dd2 = a1b < a2b ? a2b : a1b;
    float c = seg == 0 ? (float)dd1 : (seg == 1 ? (float)(dd2 - dd1) : (float)(127 - dd2));
    c = fmaxf(c, 1.f);
    pooled[((size_t)(bg0 + bb) * 768 + G * 256 + co) * 3 + seg] = pool[u] / c;
  }
}

// logits = [e1|e2|pooled_flat] @ fc_w^T + fc_b ; softmax over 19
__global__ __launch_bounds__(256) void fc_softmax(
    const float* __restrict__ e1, const float* __restrict__ e2,
    const float* __restrict__ pooled, const float* __restrict__ fcw,
    const float* __restrict__ fcb, float* __restrict__ out) {
  int b = blockIdx.x, tid = threadIdx.x;
  float acc[19];
#pragma unroll
  for (int r = 0; r < 19; ++r) acc[r] = 0.f;
  for (int j = tid; j < 2904; j += 256) {
    float v;
    if (j < 300) v = e1[b * 300 + j];
    else if (j < 600) v = e2[b * 300 + (j - 300)];
    else v = pooled[(size_t)b * 2304 + (j - 600)];
#pragma unroll
    for (int r = 0; r < 19; ++r) acc[r] = fmaf(v, fcw[r * 2904 + j], acc[r]);
  }
#pragma unroll
  for (int r = 0; r < 19; ++r) {
#pragma unroll
    for (int off = 32; off > 0; off >>= 1) acc[r] += __shfl_down(acc[r], off);
  }
  __shared__ float red[4][19];
  if ((tid & 63) == 0) {
#pragma unroll
    for (int r = 0; r < 19; ++r) red[tid >> 6][r] = acc[r];
  }
  __syncthreads();
  if (tid == 0) {
    float lg[19], mx = -1e30f;
#pragma unroll
    for (int r = 0; r < 19; ++r) {
      lg[r] = red[0][r] + red[1][r] + red[2][r] + red[3][r] + fcb[r];
      mx = fmaxf(mx, lg[r]);
    }
    float s = 0.f;
#pragma unroll
    for (int r = 0; r < 19; ++r) { lg[r] = expf(lg[r] - mx); s += lg[r]; }
    float inv = 1.f / s;
#pragma unroll
    for (int r = 0; r < 19; ++r) out[b * 19 + r] = lg[r] * inv;
  }
}

extern "C" void kernel_launch(void* const* d_in, const int* in_sizes, int n_in,
                              void* d_out, int out_size, void* d_ws, size_t ws_size,
                              hipStream_t stream) {
  const float* W   = (const float*)d_in[0];
  const int* Wp1   = (const int*)d_in[1];
  const int* Wp2   = (const int*)d_in[2];
  const float* e1  = (const float*)d_in[3];
  const float* e2  = (const float*)d_in[4];
  const int* e1p   = (const int*)d_in[5];
  const int* e2p   = (const int*)d_in[6];
  const float* pe1 = (const float*)d_in[7];
  const float* pe2 = (const float*)d_in[8];
  const float* fcw = (const float*)d_in[9];
  const float* fcb = (const float*)d_in[10];
  const float* w3  = (const float*)d_in[11];
  const float* b3  = (const float*)d_in[12];
  const float* w5  = (const float*)d_in[13];
  const float* b5  = (const float*)d_in[14];
  const float* w7  = (const float*)d_in[15];
  const float* b7  = (const float*)d_in[16];
  float* out = (float*)d_out;

  const size_t A_BYTES = (size_t)32 * NROWS * 32 * 2;          // 134,217,728
  const size_t W_BYTES = (size_t)15 * 32 * 256 * 32 * 2;       //   7,864,320
  const size_t P_BYTES = (size_t)512 * 768 * 3 * 4;            //   4,718,592
  if (ws_size < A_BYTES + W_BYTES + P_BYTES) return;           // need ~140 MiB scratch
  char* ws = (char*)d_ws;
  u16* Abf = (u16*)ws;
  u16* Wbf = (u16*)(ws + A_BYTES);
  float* pooled = (float*)(ws + A_BYTES + W_BYTES);

  build_A<<<dim3(NROWS / 4), 256, 0, stream>>>(W, Wp1, Wp2, pe1, pe2, Abf);
  build_W<<<dim3(256, 15), 256, 0, stream>>>(w3, w5, w7, Wbf);
  conv_gemm<3, 0><<<dim3(256), 512, 0, stream>>>(Abf, Wbf + (size_t)0 * 32 * 256 * 32, b3, e1p, e2p, pooled);
  conv_gemm<5, 1><<<dim3(256), 512, 0, stream>>>(Abf, Wbf + (size_t)3 * 32 * 256 * 32, b5, e1p, e2p, pooled);
  conv_gemm<7, 2><<<dim3(256), 512, 0, stream>>>(Abf, Wbf + (size_t)8 * 32 * 256 * 32, b7, e1p, e2p, pooled);
  fc_softmax<<<dim3(512), 256, 0, stream>>>(e1, e2, pooled, fcw, fcb, out);
}